// Round 16
// baseline (544.870 us; speedup 1.0000x reference)
//
#include <hip/hip_runtime.h>

#define NS 200000
#define NK 27
#define NB 1563    // ceil(NS/128): conv, shortcut, partial rows
#define EPSV 1e-5f

typedef __bf16 bf16x8 __attribute__((ext_vector_type(8)));
typedef float f32x4 __attribute__((ext_vector_type(4)));
typedef unsigned short u16;
typedef u16 u16x8 __attribute__((ext_vector_type(8)));
typedef unsigned u32;

__device__ __forceinline__ u16 f2bf(float f) {
  union { float f; unsigned u; } v; v.f = f;
  unsigned r = v.u + 0x7fffu + ((v.u >> 16) & 1u);
  return (u16)(r >> 16);
}
__device__ __forceinline__ float bf2f(u16 u) {
  union { unsigned u; float f; } v; v.u = ((unsigned)u) << 16;
  return v.f;
}

// ---- fused prep: zero stats, feats f32->bf16 (+dummy row), gidx fuse, W pack ----
__global__ void k_prep_all(const float* __restrict__ feats,
                           const int* __restrict__ in_idx, const int* __restrict__ out_idx,
                           const float* __restrict__ W1, const float* __restrict__ W2,
                           const float* __restrict__ Wsc,
                           u16* __restrict__ Xbf, int* __restrict__ gidx,
                           u16* __restrict__ Wp1, u16* __restrict__ Wp2,
                           u16* __restrict__ Wpsc, float* __restrict__ stats) {
  long i = (long)blockIdx.x * 256 + threadIdx.x;
  if (i < 768) stats[i] = 0.f;
  if (i < 64 && blockIdx.x == 0) Xbf[(long)NS * 64 + i] = (u16)0;  // dummy row
  if (i < (long)NS * 64) Xbf[i] = f2bf(feats[i]);
  if (i < (long)NK * NS) gidx[i] = (out_idx[i] != NS) ? in_idx[i] : NS;
  const int n1 = NK * 64 * 128, n2 = NK * 128 * 128, n3 = 64 * 128;
  if (i < (long)(n1 + n2 + n3)) {
    int ii = (int)i;
    const float* src; u16* dst; int f, S, C;
    if (ii < n1)           { src = W1;  dst = Wp1;  f = ii;           S = 2; C = 64; }
    else if (ii < n1 + n2) { src = W2;  dst = Wp2;  f = ii - n1;      S = 4; C = 128; }
    else                   { src = Wsc; dst = Wpsc; f = ii - n1 - n2; S = 2; C = 64; }
    int j = f & 7, l = (f >> 3) & 63, cf = (f >> 9) & 7;
    int rest = f >> 12;
    int s = rest % S, k = rest / S;
    int kk = s * 32 + (l >> 4) * 8 + j;
    dst[f] = f2bf(src[(k * C + kk) * 128 + cf * 16 + (l & 15)]);
  }
}

// ---- cooperative gather-GEMM conv: 128 rows/block, 8 waves (2m x 4n),
// wave tile 64x32 (acc[4][2]=32 regs). BOTH W and gathered-A staged into LDS
// via global_load_lds (A uses per-lane gathered SOURCE, linear dest, XOR-
// swizzled by source pre-swizzle). Double-buffered, counted-vmcnt barriers;
// A-DMA issued one full compute phase ahead -> gather latency off the
// critical path with zero register cost. ----
template <int C>
__global__ __launch_bounds__(512, (C == 64) ? 4 : 2) void k_conv(
    const u16* __restrict__ X, const u16* __restrict__ Wp,
    const int* __restrict__ gidx,
    u16* __restrict__ Y, float* __restrict__ partial) {
  constexpr int S = C / 32;              // K-slices of 32
  constexpr int UA = C / 8;              // 16B units per A row
  constexpr int LUA = (C == 64) ? 3 : 4;
  constexpr int ASL = 128 * UA * 8;      // u16 per A buffer
  constexpr int WSL = C * 128;           // u16 per W slice
  constexpr int NIT = (C == 64) ? 2 : 4; // per-thread iters for W, A, idx each
  constexpr int RPI = 512 >> LUA;        // rows covered per A-stage iter
  constexpr int WAITN = 3 * NIT;         // ops newer than the awaited group
  __shared__ alignas(16) u16 Wbuf[2 * WSL];
  __shared__ alignas(16) u16 Abuf[2 * ASL];
  __shared__ float red[512];

  const int t = threadIdx.x, w = t >> 6, l = t & 63;
  const int lr = l & 15, lh = l >> 4;
  const int wm = w >> 2, wn = w & 3;
  const int rowblk = blockIdx.x * 128;

  auto stageW = [&](int k, int p) {
    #pragma unroll
    for (int i = 0; i < NIT; ++i) {
      const u16* g = Wp + (long)k * WSL + (i * 512 + t) * 8;
      u16* d = &Wbuf[p * WSL + (i * 512 + t) * 8];
      __builtin_amdgcn_global_load_lds(
          (const __attribute__((address_space(1))) u32*)g,
          (__attribute__((address_space(3))) u32*)d, 16, 0, 0);
    }
  };
  auto loadidx = [&](int k, int (&iv)[NIT]) {
    #pragma unroll
    for (int i = 0; i < NIT; ++i) {
      int rg = rowblk + i * RPI + (t >> LUA);
      bool okr = rg < NS;
      int v = gidx[(long)k * NS + (okr ? rg : 0)];
      iv[i] = okr ? v : NS;   // invalid / OOB -> dummy zero row
    }
  };
  // gathered-A DMA: dest linear (i*512+t), source row iv[i], chunk pre-swizzled
  auto stageA = [&](int p, const int (&iv)[NIT]) {
    #pragma unroll
    for (int i = 0; i < NIT; ++i) {
      int rloc = i * RPI + (t >> LUA);
      int c = t & (UA - 1);
      int csw = c ^ (rloc & 7);
      const u16* g = X + (long)iv[i] * C + csw * 8;
      u16* d = &Abuf[p * ASL + ((i * 512 + t) * 8)];
      __builtin_amdgcn_global_load_lds(
          (const __attribute__((address_space(1))) u32*)g,
          (__attribute__((address_space(3))) u32*)d, 16, 0, 0);
    }
  };
  auto compute = [&](int p, f32x4 (&ac)[4][2]) {
    __builtin_amdgcn_s_setprio(1);
    #pragma unroll
    for (int s = 0; s < S; ++s) {
      bf16x8 a[4];
      #pragma unroll
      for (int m = 0; m < 4; ++m) {
        int row = wm * 64 + m * 16 + lr;
        int unit = row * UA + ((s * 4 + lh) ^ (row & 7));
        a[m] = *reinterpret_cast<const bf16x8*>(&Abuf[p * ASL + unit * 8]);
      }
      #pragma unroll
      for (int nf = 0; nf < 2; ++nf) {
        bf16x8 b = *reinterpret_cast<const bf16x8*>(
            &Wbuf[p * WSL + (s * 8 + wn * 2 + nf) * 512 + l * 8]);
        #pragma unroll
        for (int m = 0; m < 4; ++m)
          ac[m][nf] = __builtin_amdgcn_mfma_f32_16x16x32_bf16(a[m], b, ac[m][nf], 0, 0, 0);
      }
    }
    __builtin_amdgcn_s_setprio(0);
  };

  f32x4 acc[4][2];
  #pragma unroll
  for (int m = 0; m < 4; ++m)
    #pragma unroll
    for (int nf = 0; nf < 2; ++nf) acc[m][nf] = (f32x4){0.f, 0.f, 0.f, 0.f};

  int sv0[NIT], sv1[NIT];

  // prologue: idx(0), idx(1), W(0); wait idx(0); A(0)
  loadidx(0, sv0);
  loadidx(1, sv1);
  stageW(0, 0);
  asm volatile("s_waitcnt vmcnt(%0)" :: "i"(2 * NIT) : "memory");
  stageA(0, sv0);

  #pragma unroll 1
  for (int k = 0; k < NK - 1; k += 2) {
    // half A: compute k (buf0); stage k+1 into buf1
    stageW(k + 1, 1);
    loadidx(k + 2, sv0);
    asm volatile("s_waitcnt vmcnt(%0)" :: "i"(WAITN) : "memory");  // idx(k+1) ready
    stageA(1, sv1);
    asm volatile("s_waitcnt vmcnt(%0)\n\ts_barrier" :: "i"(WAITN) : "memory"); // W(k),A(k) done
    compute(0, acc);
    asm volatile("s_waitcnt lgkmcnt(0)\n\ts_barrier" ::: "memory");
    // half B: compute k+1 (buf1); stage k+2 into buf0
    stageW(k + 2, 0);
    { int kn = (k + 3 < NK) ? k + 3 : NK - 1; loadidx(kn, sv1); }
    asm volatile("s_waitcnt vmcnt(%0)" :: "i"(WAITN) : "memory");  // idx(k+2) ready
    stageA(0, sv0);
    asm volatile("s_waitcnt vmcnt(%0)\n\ts_barrier" :: "i"(WAITN) : "memory");
    compute(1, acc);
    asm volatile("s_waitcnt lgkmcnt(0)\n\ts_barrier" ::: "memory");
  }
  // tail k = 26 (staged into buf0 by last half B)
  asm volatile("s_waitcnt vmcnt(0)\n\ts_barrier" ::: "memory");
  compute(0, acc);

  // ---- epilogue: stores + fused per-block stats partials ----
  #pragma unroll
  for (int m = 0; m < 4; ++m)
    #pragma unroll
    for (int nf = 0; nf < 2; ++nf) {
      int ch = wn * 32 + nf * 16 + lr;
      #pragma unroll
      for (int r = 0; r < 4; ++r) {
        int row = rowblk + wm * 64 + m * 16 + lh * 4 + r;
        if (row < NS) Y[(long)row * 128 + ch] = f2bf(acc[m][nf][r]);
      }
    }
  #pragma unroll
  for (int nf = 0; nf < 2; ++nf) {
    float s = 0.f, q = 0.f;
    #pragma unroll
    for (int m = 0; m < 4; ++m)
      #pragma unroll
      for (int r = 0; r < 4; ++r) { float v = acc[m][nf][r]; s += v; q += v * v; }
    s += __shfl_xor(s, 16); s += __shfl_xor(s, 32);
    q += __shfl_xor(q, 16); q += __shfl_xor(q, 32);
    if (lh == 0) {
      red[w * 64 + nf * 16 + lr] = s;
      red[w * 64 + 32 + nf * 16 + lr] = q;
    }
  }
  __syncthreads();
  if (t < 256) {
    int isq = t >> 7, c = t & 127;
    int wnc = c >> 5, c31 = c & 31;
    partial[(long)blockIdx.x * 256 + t] =
        red[wnc * 64 + isq * 32 + c31] + red[(4 + wnc) * 64 + isq * 32 + c31];
  }
}

// ---- standalone shortcut: SC = X @ Wsc, 128 rows/block, 4 waves x 32 rows ----
__global__ __launch_bounds__(256, 2) void k_sc(
    const u16* __restrict__ X, const u16* __restrict__ Wpsc,
    u16* __restrict__ SCb, float* __restrict__ partial) {
  __shared__ float red[1024];
  const int t = threadIdx.x, w = t >> 6, l = t & 63;
  const int lr = l & 15, lh = l >> 4;
  const int rowbase = blockIdx.x * 128 + w * 32;
  const int laneoff = l * 8;

  bf16x8 ai[2][2];
  #pragma unroll
  for (int m = 0; m < 2; ++m) {
    int r = rowbase + m * 16 + lr;
    #pragma unroll
    for (int s = 0; s < 2; ++s) ai[m][s] = bf16x8{};
    if (r < NS) {
      const u16* rowp = X + (long)r * 64 + lh * 8;
      ai[m][0] = *reinterpret_cast<const bf16x8*>(rowp);
      ai[m][1] = *reinterpret_cast<const bf16x8*>(rowp + 32);
    }
  }
  f32x4 acc[2][8];
  #pragma unroll
  for (int m = 0; m < 2; ++m)
    #pragma unroll
    for (int cf = 0; cf < 8; ++cf) acc[m][cf] = (f32x4){0.f, 0.f, 0.f, 0.f};
  #pragma unroll
  for (int s = 0; s < 2; ++s)
    #pragma unroll
    for (int cf = 0; cf < 8; ++cf) {
      bf16x8 b = *reinterpret_cast<const bf16x8*>(Wpsc + (s * 8 + cf) * 512 + laneoff);
      acc[0][cf] = __builtin_amdgcn_mfma_f32_16x16x32_bf16(ai[0][s], b, acc[0][cf], 0, 0, 0);
      acc[1][cf] = __builtin_amdgcn_mfma_f32_16x16x32_bf16(ai[1][s], b, acc[1][cf], 0, 0, 0);
    }
  #pragma unroll
  for (int m = 0; m < 2; ++m)
    #pragma unroll
    for (int cf = 0; cf < 8; ++cf) {
      int ch = cf * 16 + lr;
      #pragma unroll
      for (int r = 0; r < 4; ++r) {
        int row = rowbase + m * 16 + lh * 4 + r;
        if (row < NS) SCb[(long)row * 128 + ch] = f2bf(acc[m][cf][r]);
      }
    }
  #pragma unroll
  for (int cf = 0; cf < 8; ++cf) {
    float s = 0.f, q = 0.f;
    #pragma unroll
    for (int m = 0; m < 2; ++m)
      #pragma unroll
      for (int r = 0; r < 4; ++r) { float v = acc[m][cf][r]; s += v; q += v * v; }
    s += __shfl_xor(s, 16); s += __shfl_xor(s, 32);
    q += __shfl_xor(q, 16); q += __shfl_xor(q, 32);
    if (lh == 0) {
      red[w * 256 + cf * 16 + lr] = s;
      red[w * 256 + 128 + cf * 16 + lr] = q;
    }
  }
  __syncthreads();
  if (t < 256)
    partial[(long)blockIdx.x * 256 + t] =
        red[t] + red[256 + t] + red[512 + t] + red[768 + t];
}

// ---- deterministic reductions (rtmp stride 512) ----
__global__ void k_red1x2(const float* __restrict__ pa, const float* __restrict__ pb,
                         float* __restrict__ tmp) {
  int c = threadIdx.x;
  const float* p = (blockIdx.x == 0) ? pa : pb;
  int roff = (blockIdx.x == 0) ? 0 : 256;
  float s = 0.f;
  for (int r = blockIdx.y; r < NB; r += 32) s += p[(long)r * 256 + c];
  tmp[(long)blockIdx.y * 512 + roff + c] = s;
}
__global__ void k_red1(const float* __restrict__ part, float* __restrict__ tmp) {
  int c = threadIdx.x;
  float s = 0.f;
  for (int r = blockIdx.y; r < NB; r += 32) s += part[(long)r * 256 + c];
  tmp[(long)blockIdx.y * 512 + c] = s;
}
__global__ void k_red2(const float* __restrict__ tmp, float* __restrict__ out) {
  int c = blockIdx.x * 256 + threadIdx.x;
  float s = 0.f;
  #pragma unroll
  for (int r = 0; r < 32; ++r) s += tmp[(long)r * 512 + c];
  out[c] = s;
}

// ---- h = relu(bn1(y1)) -> bf16 (+ zero dummy row NS) ----
__global__ void k_bnrelu(const u16* __restrict__ Y1, const float* __restrict__ stats,
                         const float* __restrict__ g, const float* __restrict__ b,
                         u16* __restrict__ H) {
  long i8 = (long)blockIdx.x * 256 + threadIdx.x;
  const long tot = (long)(NS + 1) * 16;
  if (i8 >= tot) return;
  long row = i8 >> 4;
  u16x8 o;
  if (row < NS) {
    int ch0 = ((int)i8 & 15) * 8;
    u16x8 y = *reinterpret_cast<const u16x8*>(Y1 + i8 * 8);
    #pragma unroll
    for (int e = 0; e < 8; ++e) {
      int ch = ch0 + e;
      float m = stats[ch] * (1.f / NS);
      float var = stats[128 + ch] * (1.f / NS) - m * m;
      float a = g[ch] * rsqrtf(var + EPSV);
      float bb = b[ch] - m * a;
      float h = bf2f(y[e]) * a + bb;
      o[e] = f2bf(h > 0.f ? h : 0.f);
    }
  } else {
    #pragma unroll
    for (int e = 0; e < 8; ++e) o[e] = (u16)0;
  }
  *reinterpret_cast<u16x8*>(H + i8 * 8) = o;
}

// ---- out = relu(bn2(y2) + bnsc(sc)) f32, 16B loads ----
__global__ void k_final(const u16* __restrict__ Y2, const u16* __restrict__ SCb,
                        const float* __restrict__ stats,
                        const float* __restrict__ g2, const float* __restrict__ b2,
                        const float* __restrict__ gsc, const float* __restrict__ bsc,
                        float* __restrict__ out) {
  long i8 = (long)blockIdx.x * 256 + threadIdx.x;
  if (i8 >= (long)NS * 16) return;
  int ch0 = ((int)i8 & 15) * 8;
  u16x8 y = *reinterpret_cast<const u16x8*>(Y2 + i8 * 8);
  u16x8 s = *reinterpret_cast<const u16x8*>(SCb + i8 * 8);
  f32x4 o0, o1;
  #pragma unroll
  for (int e = 0; e < 8; ++e) {
    int ch = ch0 + e;
    float m2 = stats[512 + ch] * (1.f / NS);
    float v2 = stats[640 + ch] * (1.f / NS) - m2 * m2;
    float a2 = g2[ch] * rsqrtf(v2 + EPSV);
    float msc = stats[256 + ch] * (1.f / NS);
    float vsc = stats[384 + ch] * (1.f / NS) - msc * msc;
    float asc = gsc[ch] * rsqrtf(vsc + EPSV);
    float val = bf2f(y[e]) * a2 + (b2[ch] - m2 * a2)
              + bf2f(s[e]) * asc + (bsc[ch] - msc * asc);
    float rv = val > 0.f ? val : 0.f;
    if (e < 4) o0[e] = rv; else o1[e - 4] = rv;
  }
  *reinterpret_cast<f32x4*>(out + i8 * 8) = o0;
  *reinterpret_cast<f32x4*>(out + i8 * 8 + 4) = o1;
}

extern "C" void kernel_launch(void* const* d_in, const int* in_sizes, int n_in,
                              void* d_out, int out_size, void* d_ws, size_t ws_size,
                              hipStream_t stream) {
  const float* feats = (const float*)d_in[0];
  const int* in_idx  = (const int*)d_in[1];
  const int* out_idx = (const int*)d_in[2];
  const float* W1  = (const float*)d_in[3];
  const float* g1  = (const float*)d_in[4];
  const float* b1  = (const float*)d_in[5];
  const float* W2  = (const float*)d_in[6];
  const float* g2  = (const float*)d_in[7];
  const float* b2  = (const float*)d_in[8];
  const float* Wsc = (const float*)d_in[9];
  const float* gsc = (const float*)d_in[10];
  const float* bsc = (const float*)d_in[11];

  char* ws = (char*)d_ws;
  size_t off = 0;
  auto alloc = [&](size_t bytes) {
    void* p = ws + off; off += (bytes + 255) & ~(size_t)255; return p;
  };
  float* stats = (float*)alloc(768 * 4);               // [s1,q1,ssc,qsc,s2,q2] x128
  float* rtmp  = (float*)alloc(32 * 512 * 4);          // reduce stage-1 (stride 512)
  u16* Xbf  = (u16*)alloc((size_t)(NS + 1) * 64 * 2);
  u16* SCbf = (u16*)alloc((size_t)NS * 128 * 2);
  u16* Hbf  = (u16*)alloc((size_t)(NS + 1) * 128 * 2);
  u16* Y2bf = (u16*)alloc((size_t)NS * 128 * 2);
  u16* Wp1  = (u16*)alloc((size_t)NK * 64 * 128 * 2);
  u16* Wp2  = (u16*)alloc((size_t)NK * 128 * 128 * 2);
  u16* Wpsc = (u16*)alloc((size_t)64 * 128 * 2);
  // d_out hosts y1 bf16 (51.2MB) + fused gidx (21.6MB); k_final overwrites
  u16* Y1bf = (u16*)d_out;
  int* gidx = (int*)((char*)d_out + (size_t)NS * 128 * 2);
  // partials alias Y2bf / Xbf regions (all consumed before their writers run)
  float* part1  = (float*)Y2bf;                  // conv1: 1563x256
  float* partsc = part1 + (size_t)NB * 256;      // sc:   1563x256
  float* part2  = (float*)Xbf;                   // conv2 (Xbf dead after conv1)

  hipLaunchKernelGGL(k_prep_all, dim3(50000), dim3(256), 0, stream,
                     feats, in_idx, out_idx, W1, W2, Wsc,
                     Xbf, gidx, Wp1, Wp2, Wpsc, stats);
  hipLaunchKernelGGL(k_sc, dim3(NB), dim3(256), 0, stream, Xbf, Wpsc, SCbf, partsc);
  hipLaunchKernelGGL((k_conv<64>), dim3(NB), dim3(512), 0, stream,
                     Xbf, Wp1, gidx, Y1bf, part1);
  hipLaunchKernelGGL(k_red1x2, dim3(2, 32), dim3(256), 0, stream, part1, partsc, rtmp);
  hipLaunchKernelGGL(k_red2, dim3(2), dim3(256), 0, stream, rtmp, stats);
  hipLaunchKernelGGL(k_bnrelu, dim3(12501), dim3(256), 0, stream, Y1bf, stats, g1, b1, Hbf);
  hipLaunchKernelGGL((k_conv<128>), dim3(NB), dim3(512), 0, stream,
                     Hbf, Wp2, gidx, Y2bf, part2);
  hipLaunchKernelGGL(k_red1, dim3(1, 32), dim3(256), 0, stream, part2, rtmp);
  hipLaunchKernelGGL(k_red2, dim3(1), dim3(256), 0, stream, rtmp, stats + 512);
  hipLaunchKernelGGL(k_final, dim3(12500), dim3(256), 0, stream,
                     Y2bf, SCbf, stats, g2, b2, gsc, bsc, (float*)d_out);
}

// Round 17
// 420.024 us; speedup vs baseline: 1.2972x; 1.2972x over previous
//
#include <hip/hip_runtime.h>

#define NS 200000
#define NK 27
#define NB 782     // ceil(NS/256)  - conv blocks
#define NBSC 1563  // ceil(NS/128)  - shortcut blocks
#define EPSV 1e-5f

typedef __bf16 bf16x8 __attribute__((ext_vector_type(8)));
typedef float f32x4 __attribute__((ext_vector_type(4)));
typedef unsigned short u16;
typedef u16 u16x8 __attribute__((ext_vector_type(8)));
typedef u16 u16x4 __attribute__((ext_vector_type(4)));
typedef unsigned u32;

__device__ __forceinline__ u16 f2bf(float f) {
  union { float f; unsigned u; } v; v.f = f;
  unsigned r = v.u + 0x7fffu + ((v.u >> 16) & 1u);
  return (u16)(r >> 16);
}
__device__ __forceinline__ float bf2f(u16 u) {
  union { unsigned u; float f; } v; v.u = ((unsigned)u) << 16;
  return v.f;
}

// ---- fused prep: zero stats, feats f32->bf16, gidx fuse, W pack ----
// packed f = ((k*S+s)*8+cf)*512 + l*8 + j  <->  W[k][s*32+(l>>4)*8+j][cf*16+(l&15)]
__global__ void k_prep_all(const float* __restrict__ feats,
                           const int* __restrict__ in_idx, const int* __restrict__ out_idx,
                           const float* __restrict__ W1, const float* __restrict__ W2,
                           const float* __restrict__ Wsc,
                           u16* __restrict__ Xbf, int* __restrict__ gidx,
                           u16* __restrict__ Wp1, u16* __restrict__ Wp2,
                           u16* __restrict__ Wpsc, float* __restrict__ stats) {
  long i = (long)blockIdx.x * 256 + threadIdx.x;
  if (i < 768) stats[i] = 0.f;
  if (i < (long)NS * 64) Xbf[i] = f2bf(feats[i]);
  if (i < (long)NK * NS) gidx[i] = (out_idx[i] != NS) ? in_idx[i] : NS;
  const int n1 = NK * 64 * 128, n2 = NK * 128 * 128, n3 = 64 * 128;
  if (i < (long)(n1 + n2 + n3)) {
    int ii = (int)i;
    const float* src; u16* dst; int f, S, C;
    if (ii < n1)           { src = W1;  dst = Wp1;  f = ii;           S = 2; C = 64; }
    else if (ii < n1 + n2) { src = W2;  dst = Wp2;  f = ii - n1;      S = 4; C = 128; }
    else                   { src = Wsc; dst = Wpsc; f = ii - n1 - n2; S = 2; C = 64; }
    int j = f & 7, l = (f >> 3) & 63, cf = (f >> 9) & 7;
    int rest = f >> 12;
    int s = rest % S, k = rest / S;
    int kk = s * 32 + (l >> 4) * 8 + j;
    dst[f] = f2bf(src[(k * C + kk) * 128 + cf * 16 + (l & 15)]);
  }
}

// ---- gather-GEMM conv (R9/R14 optimum, verbatim): 4 waves x 64 rows,
// wave tile 64x128. W in LDS (dbuf, global_load_lds, lane-linear); A gathered
// per-lane, conditional; single A reg buffer; counted-vmcnt barriers. ----
template <int C>
__global__ __launch_bounds__(256, 2) void k_conv(
    const u16* __restrict__ X, const u16* __restrict__ Wp,
    const int* __restrict__ gidx,
    u16* __restrict__ Y, float* __restrict__ partial) {
  constexpr int S = C / 32;
  constexpr int SLICE = C * 128;
  constexpr int NST = C / 16;
  constexpr int WAITN = NST + 4;
  __shared__ alignas(16) u16 Wbuf[2 * SLICE];
  __shared__ float red[1024];

  const int t = threadIdx.x, w = t >> 6, l = t & 63;
  const int lr = l & 15, lh = l >> 4;
  const int rowbase = blockIdx.x * 256 + w * 64;
  const int laneoff = l * 8;

  int rc[4]; bool ok[4];
  #pragma unroll
  for (int m = 0; m < 4; ++m) {
    int r = rowbase + m * 16 + lr;
    ok[m] = r < NS;
    rc[m] = ok[m] ? r : 0;
  }

  auto stage = [&](int k, int p) {
    #pragma unroll
    for (int i = 0; i < NST; ++i) {
      const u16* g = Wp + k * SLICE + (w * NST + i) * 512 + laneoff;
      u16* d = &Wbuf[p * SLICE + (w * NST + i) * 512];
      __builtin_amdgcn_global_load_lds(
          (const __attribute__((address_space(1))) u32*)g,
          (__attribute__((address_space(3))) u32*)d, 16, 0, 0);
    }
  };
  auto loadidx = [&](int k, int (&dst)[4]) {
    #pragma unroll
    for (int m = 0; m < 4; ++m) {
      int v = gidx[k * NS + rc[m]];
      dst[m] = ok[m] ? v : NS;
    }
  };
  auto gather = [&](const int (&src)[4], bf16x8 (&a)[4][S]) {
    #pragma unroll
    for (int m = 0; m < 4; ++m) {
      #pragma unroll
      for (int s = 0; s < S; ++s) a[m][s] = bf16x8{};
      if (src[m] != NS) {
        const u16* rowp = X + src[m] * C + lh * 8;
        #pragma unroll
        for (int s = 0; s < S; ++s)
          a[m][s] = *reinterpret_cast<const bf16x8*>(rowp + s * 32);
      }
    }
  };
  auto compute = [&](int p, const bf16x8 (&a)[4][S], f32x4 (&ac)[4][8]) {
    __builtin_amdgcn_s_setprio(1);
    #pragma unroll
    for (int s = 0; s < S; ++s)
      #pragma unroll
      for (int cf = 0; cf < 8; ++cf) {
        bf16x8 b = *reinterpret_cast<const bf16x8*>(
            &Wbuf[p * SLICE + (s * 8 + cf) * 512 + laneoff]);
        #pragma unroll
        for (int m = 0; m < 4; ++m)
          ac[m][cf] = __builtin_amdgcn_mfma_f32_16x16x32_bf16(a[m][s], b, ac[m][cf], 0, 0, 0);
      }
    __builtin_amdgcn_s_setprio(0);
  };

  f32x4 acc[4][8];
  #pragma unroll
  for (int m = 0; m < 4; ++m)
    #pragma unroll
    for (int cf = 0; cf < 8; ++cf) acc[m][cf] = (f32x4){0.f, 0.f, 0.f, 0.f};

  bf16x8 av[4][S];
  int sv0[4], sv1[4];

  loadidx(0, sv0);
  stage(0, 0);
  loadidx(1, sv1);
  gather(sv0, av);

  #pragma unroll 1
  for (int k = 0; k < NK - 1; k += 2) {
    stage(k + 1, 1);
    loadidx(k + 2, sv0);
    asm volatile("s_waitcnt vmcnt(%0)\n\ts_barrier" :: "i"(WAITN) : "memory");
    compute(0, av, acc);
    gather(sv1, av);
    asm volatile("s_waitcnt lgkmcnt(0)\n\ts_barrier" ::: "memory");
    stage(k + 2, 0);
    { int kn = (k + 3 < NK) ? k + 3 : NK - 1; loadidx(kn, sv1); }
    asm volatile("s_waitcnt vmcnt(%0)\n\ts_barrier" :: "i"(WAITN) : "memory");
    compute(1, av, acc);
    gather(sv0, av);
    asm volatile("s_waitcnt lgkmcnt(0)\n\ts_barrier" ::: "memory");
  }
  asm volatile("s_waitcnt vmcnt(0)\n\ts_barrier" ::: "memory");
  compute(0, av, acc);

  #pragma unroll
  for (int m = 0; m < 4; ++m)
    #pragma unroll
    for (int cf = 0; cf < 8; ++cf) {
      int ch = cf * 16 + lr;
      #pragma unroll
      for (int r = 0; r < 4; ++r) {
        int row = rowbase + m * 16 + lh * 4 + r;
        if (row < NS) Y[row * 128 + ch] = f2bf(acc[m][cf][r]);
      }
    }
  #pragma unroll
  for (int cf = 0; cf < 8; ++cf) {
    float s = 0.f, q = 0.f;
    #pragma unroll
    for (int m = 0; m < 4; ++m)
      #pragma unroll
      for (int r = 0; r < 4; ++r) { float v = acc[m][cf][r]; s += v; q += v * v; }
    s += __shfl_xor(s, 16); s += __shfl_xor(s, 32);
    q += __shfl_xor(q, 16); q += __shfl_xor(q, 32);
    if (lh == 0) {
      red[w * 256 + cf * 16 + lr] = s;
      red[w * 256 + 128 + cf * 16 + lr] = q;
    }
  }
  __syncthreads();
  if (t < 256)
    partial[blockIdx.x * 256 + t] =
        red[t] + red[256 + t] + red[512 + t] + red[768 + t];
}

// ---- standalone shortcut: SC = X @ Wsc, 128 rows/block, 4 waves x 32 rows ----
__global__ __launch_bounds__(256, 2) void k_sc(
    const u16* __restrict__ X, const u16* __restrict__ Wpsc,
    u16* __restrict__ SCb, float* __restrict__ partial) {
  __shared__ float red[1024];
  const int t = threadIdx.x, w = t >> 6, l = t & 63;
  const int lr = l & 15, lh = l >> 4;
  const int rowbase = blockIdx.x * 128 + w * 32;
  const int laneoff = l * 8;

  bf16x8 ai[2][2];
  #pragma unroll
  for (int m = 0; m < 2; ++m) {
    int r = rowbase + m * 16 + lr;
    #pragma unroll
    for (int s = 0; s < 2; ++s) ai[m][s] = bf16x8{};
    if (r < NS) {
      const u16* rowp = X + r * 64 + lh * 8;
      ai[m][0] = *reinterpret_cast<const bf16x8*>(rowp);
      ai[m][1] = *reinterpret_cast<const bf16x8*>(rowp + 32);
    }
  }
  f32x4 acc[2][8];
  #pragma unroll
  for (int m = 0; m < 2; ++m)
    #pragma unroll
    for (int cf = 0; cf < 8; ++cf) acc[m][cf] = (f32x4){0.f, 0.f, 0.f, 0.f};
  #pragma unroll
  for (int s = 0; s < 2; ++s)
    #pragma unroll
    for (int cf = 0; cf < 8; ++cf) {
      bf16x8 b = *reinterpret_cast<const bf16x8*>(Wpsc + (s * 8 + cf) * 512 + laneoff);
      acc[0][cf] = __builtin_amdgcn_mfma_f32_16x16x32_bf16(ai[0][s], b, acc[0][cf], 0, 0, 0);
      acc[1][cf] = __builtin_amdgcn_mfma_f32_16x16x32_bf16(ai[1][s], b, acc[1][cf], 0, 0, 0);
    }
  #pragma unroll
  for (int m = 0; m < 2; ++m)
    #pragma unroll
    for (int cf = 0; cf < 8; ++cf) {
      int ch = cf * 16 + lr;
      #pragma unroll
      for (int r = 0; r < 4; ++r) {
        int row = rowbase + m * 16 + lh * 4 + r;
        if (row < NS) SCb[row * 128 + ch] = f2bf(acc[m][cf][r]);
      }
    }
  #pragma unroll
  for (int cf = 0; cf < 8; ++cf) {
    float s = 0.f, q = 0.f;
    #pragma unroll
    for (int m = 0; m < 2; ++m)
      #pragma unroll
      for (int r = 0; r < 4; ++r) { float v = acc[m][cf][r]; s += v; q += v * v; }
    s += __shfl_xor(s, 16); s += __shfl_xor(s, 32);
    q += __shfl_xor(q, 16); q += __shfl_xor(q, 32);
    if (lh == 0) {
      red[w * 256 + cf * 16 + lr] = s;
      red[w * 256 + 128 + cf * 16 + lr] = q;
    }
  }
  __syncthreads();
  if (t < 256)
    partial[(long)blockIdx.x * 256 + t] =
        red[t] + red[256 + t] + red[512 + t] + red[768 + t];
}

// ---- deterministic reductions (rtmp stride 512) ----
__global__ void k_red1x2(const float* __restrict__ pa, const float* __restrict__ pb,
                         float* __restrict__ tmp) {
  int c = threadIdx.x;
  const float* p = (blockIdx.x == 0) ? pa : pb;
  int nrows = (blockIdx.x == 0) ? NB : NBSC;
  int roff  = (blockIdx.x == 0) ? 0 : 256;
  float s = 0.f;
  for (int r = blockIdx.y; r < nrows; r += 32) s += p[(long)r * 256 + c];
  tmp[(long)blockIdx.y * 512 + roff + c] = s;
}
__global__ void k_red1(const float* __restrict__ part, float* __restrict__ tmp,
                       int nrows) {
  int c = threadIdx.x;
  float s = 0.f;
  for (int r = blockIdx.y; r < nrows; r += 32) s += part[(long)r * 256 + c];
  tmp[(long)blockIdx.y * 512 + c] = s;
}
__global__ void k_red2(const float* __restrict__ tmp, float* __restrict__ out) {
  int c = blockIdx.x * 256 + threadIdx.x;
  float s = 0.f;
  #pragma unroll
  for (int r = 0; r < 32; ++r) s += tmp[(long)r * 512 + c];
  out[c] = s;
}

// ---- h = relu(bn1(y1)) -> bf16 ----
__global__ void k_bnrelu(const u16* __restrict__ Y1, const float* __restrict__ stats,
                         const float* __restrict__ g, const float* __restrict__ b,
                         u16* __restrict__ H) {
  long i8 = (long)blockIdx.x * 256 + threadIdx.x;
  const long tot = (long)NS * 16;
  if (i8 >= tot) return;
  int ch0 = ((int)i8 & 15) * 8;
  u16x8 y = *reinterpret_cast<const u16x8*>(Y1 + i8 * 8);
  u16x8 o;
  #pragma unroll
  for (int e = 0; e < 8; ++e) {
    int ch = ch0 + e;
    float m = stats[ch] * (1.f / NS);
    float var = stats[128 + ch] * (1.f / NS) - m * m;
    float a = g[ch] * rsqrtf(var + EPSV);
    float bb = b[ch] - m * a;
    float h = bf2f(y[e]) * a + bb;
    o[e] = f2bf(h > 0.f ? h : 0.f);
  }
  *reinterpret_cast<u16x8*>(H + i8 * 8) = o;
}

// ---- out = relu(bn2(y2) + bnsc(sc)) f32, 16B loads ----
__global__ void k_final(const u16* __restrict__ Y2, const u16* __restrict__ SCb,
                        const float* __restrict__ stats,
                        const float* __restrict__ g2, const float* __restrict__ b2,
                        const float* __restrict__ gsc, const float* __restrict__ bsc,
                        float* __restrict__ out) {
  long i8 = (long)blockIdx.x * 256 + threadIdx.x;
  if (i8 >= (long)NS * 16) return;
  int ch0 = ((int)i8 & 15) * 8;
  u16x8 y = *reinterpret_cast<const u16x8*>(Y2 + i8 * 8);
  u16x8 s = *reinterpret_cast<const u16x8*>(SCb + i8 * 8);
  f32x4 o0, o1;
  #pragma unroll
  for (int e = 0; e < 8; ++e) {
    int ch = ch0 + e;
    float m2 = stats[512 + ch] * (1.f / NS);
    float v2 = stats[640 + ch] * (1.f / NS) - m2 * m2;
    float a2 = g2[ch] * rsqrtf(v2 + EPSV);
    float msc = stats[256 + ch] * (1.f / NS);
    float vsc = stats[384 + ch] * (1.f / NS) - msc * msc;
    float asc = gsc[ch] * rsqrtf(vsc + EPSV);
    float val = bf2f(y[e]) * a2 + (b2[ch] - m2 * a2)
              + bf2f(s[e]) * asc + (bsc[ch] - msc * asc);
    float rv = val > 0.f ? val : 0.f;
    if (e < 4) o0[e] = rv; else o1[e - 4] = rv;
  }
  *reinterpret_cast<f32x4*>(out + i8 * 8) = o0;
  *reinterpret_cast<f32x4*>(out + i8 * 8 + 4) = o1;
}

extern "C" void kernel_launch(void* const* d_in, const int* in_sizes, int n_in,
                              void* d_out, int out_size, void* d_ws, size_t ws_size,
                              hipStream_t stream) {
  const float* feats = (const float*)d_in[0];
  const int* in_idx  = (const int*)d_in[1];
  const int* out_idx = (const int*)d_in[2];
  const float* W1  = (const float*)d_in[3];
  const float* g1  = (const float*)d_in[4];
  const float* b1  = (const float*)d_in[5];
  const float* W2  = (const float*)d_in[6];
  const float* g2  = (const float*)d_in[7];
  const float* b2  = (const float*)d_in[8];
  const float* Wsc = (const float*)d_in[9];
  const float* gsc = (const float*)d_in[10];
  const float* bsc = (const float*)d_in[11];

  char* ws = (char*)d_ws;
  size_t off = 0;
  auto alloc = [&](size_t bytes) {
    void* p = ws + off; off += (bytes + 255) & ~(size_t)255; return p;
  };
  float* stats = (float*)alloc(768 * 4);               // [s1,q1,ssc,qsc,s2,q2] x128
  float* rtmp  = (float*)alloc(32 * 512 * 4);          // reduce stage-1 (stride 512)
  u16* Xbf  = (u16*)alloc((size_t)NS * 64 * 2);
  u16* SCbf = (u16*)alloc((size_t)NS * 128 * 2);
  u16* Hbf  = (u16*)alloc((size_t)NS * 128 * 2);
  u16* Y2bf = (u16*)alloc((size_t)NS * 128 * 2);
  u16* Wp1  = (u16*)alloc((size_t)NK * 64 * 128 * 2);
  u16* Wp2  = (u16*)alloc((size_t)NK * 128 * 128 * 2);
  u16* Wpsc = (u16*)alloc((size_t)64 * 128 * 2);
  // d_out hosts y1 bf16 (51.2MB) + fused gidx (21.6MB); k_final overwrites
  u16* Y1bf = (u16*)d_out;
  int* gidx = (int*)((char*)d_out + (size_t)NS * 128 * 2);
  // partials alias Y2bf / Xbf regions (all consumed before their writers run)
  float* part1  = (float*)Y2bf;                  // conv1: 782x256
  float* partsc = part1 + (size_t)NB * 256;      // sc:   1563x256
  float* part2  = (float*)Xbf;                   // conv2 (Xbf dead after conv1)

  hipLaunchKernelGGL(k_prep_all, dim3(50000), dim3(256), 0, stream,
                     feats, in_idx, out_idx, W1, W2, Wsc,
                     Xbf, gidx, Wp1, Wp2, Wpsc, stats);
  hipLaunchKernelGGL(k_sc, dim3(NBSC), dim3(256), 0, stream, Xbf, Wpsc, SCbf, partsc);
  hipLaunchKernelGGL((k_conv<64>), dim3(NB), dim3(256), 0, stream,
                     Xbf, Wp1, gidx, Y1bf, part1);
  hipLaunchKernelGGL(k_red1x2, dim3(2, 32), dim3(256), 0, stream, part1, partsc, rtmp);
  hipLaunchKernelGGL(k_red2, dim3(2), dim3(256), 0, stream, rtmp, stats);
  hipLaunchKernelGGL(k_bnrelu, dim3(12500), dim3(256), 0, stream, Y1bf, stats, g1, b1, Hbf);
  hipLaunchKernelGGL((k_conv<128>), dim3(NB), dim3(256), 0, stream,
                     Hbf, Wp2, gidx, Y2bf, part2);
  hipLaunchKernelGGL(k_red1, dim3(1, 32), dim3(256), 0, stream, part2, rtmp, NB);
  hipLaunchKernelGGL(k_red2, dim3(1), dim3(256), 0, stream, rtmp, stats + 512);
  hipLaunchKernelGGL(k_final, dim3(12500), dim3(256), 0, stream,
                     Y2bf, SCbf, stats, g2, b2, gsc, bsc, (float*)d_out);
}

// Round 18
// 405.411 us; speedup vs baseline: 1.3440x; 1.0360x over previous
//
#include <hip/hip_runtime.h>

#define NS 200000
#define NK 27
#define NB 782     // ceil(NS/256)  - conv blocks
#define NBSC 1563  // ceil(NS/128)  - shortcut blocks
#define EPSV 1e-5f

typedef __bf16 bf16x8 __attribute__((ext_vector_type(8)));
typedef float f32x4 __attribute__((ext_vector_type(4)));
typedef unsigned short u16;
typedef u16 u16x8 __attribute__((ext_vector_type(8)));
typedef u16 u16x4 __attribute__((ext_vector_type(4)));
typedef unsigned u32;

__device__ __forceinline__ u16 f2bf(float f) {
  union { float f; unsigned u; } v; v.f = f;
  unsigned r = v.u + 0x7fffu + ((v.u >> 16) & 1u);
  return (u16)(r >> 16);
}
__device__ __forceinline__ float bf2f(u16 u) {
  union { unsigned u; float f; } v; v.u = ((unsigned)u) << 16;
  return v.f;
}

// ---- fused prep: zero stats, feats f32->bf16, gidx fuse, W pack ----
// packed f = ((k*S+s)*8+cf)*512 + l*8 + j  <->  W[k][s*32+(l>>4)*8+j][cf*16+(l&15)]
__global__ void k_prep_all(const float* __restrict__ feats,
                           const int* __restrict__ in_idx, const int* __restrict__ out_idx,
                           const float* __restrict__ W1, const float* __restrict__ W2,
                           const float* __restrict__ Wsc,
                           u16* __restrict__ Xbf, int* __restrict__ gidx,
                           u16* __restrict__ Wp1, u16* __restrict__ Wp2,
                           u16* __restrict__ Wpsc, float* __restrict__ stats) {
  long i = (long)blockIdx.x * 256 + threadIdx.x;
  if (i < 768) stats[i] = 0.f;
  if (i < (long)NS * 64) Xbf[i] = f2bf(feats[i]);
  if (i < (long)NK * NS) gidx[i] = (out_idx[i] != NS) ? in_idx[i] : NS;
  const int n1 = NK * 64 * 128, n2 = NK * 128 * 128, n3 = 64 * 128;
  if (i < (long)(n1 + n2 + n3)) {
    int ii = (int)i;
    const float* src; u16* dst; int f, S, C;
    if (ii < n1)           { src = W1;  dst = Wp1;  f = ii;           S = 2; C = 64; }
    else if (ii < n1 + n2) { src = W2;  dst = Wp2;  f = ii - n1;      S = 4; C = 128; }
    else                   { src = Wsc; dst = Wpsc; f = ii - n1 - n2; S = 2; C = 64; }
    int j = f & 7, l = (f >> 3) & 63, cf = (f >> 9) & 7;
    int rest = f >> 12;
    int s = rest % S, k = rest / S;
    int kk = s * 32 + (l >> 4) * 8 + j;
    dst[f] = f2bf(src[(k * C + kk) * 128 + cf * 16 + (l & 15)]);
  }
}

// ---- sc block body: SC = X @ Wsc, 128 rows, 4 waves x 32 rows ----
__device__ __forceinline__ void sc_body(
    int bid, const u16* __restrict__ X, const u16* __restrict__ Wpsc,
    u16* __restrict__ SCb, float* __restrict__ partial, float* red) {
  const int t = threadIdx.x, w = t >> 6, l = t & 63;
  const int lr = l & 15, lh = l >> 4;
  const int rowbase = bid * 128 + w * 32;
  const int laneoff = l * 8;

  bf16x8 ai[2][2];
  #pragma unroll
  for (int m = 0; m < 2; ++m) {
    int r = rowbase + m * 16 + lr;
    #pragma unroll
    for (int s = 0; s < 2; ++s) ai[m][s] = bf16x8{};
    if (r < NS) {
      const u16* rowp = X + r * 64 + lh * 8;
      ai[m][0] = *reinterpret_cast<const bf16x8*>(rowp);
      ai[m][1] = *reinterpret_cast<const bf16x8*>(rowp + 32);
    }
  }
  f32x4 acc[2][8];
  #pragma unroll
  for (int m = 0; m < 2; ++m)
    #pragma unroll
    for (int cf = 0; cf < 8; ++cf) acc[m][cf] = (f32x4){0.f, 0.f, 0.f, 0.f};
  #pragma unroll
  for (int s = 0; s < 2; ++s)
    #pragma unroll
    for (int cf = 0; cf < 8; ++cf) {
      bf16x8 b = *reinterpret_cast<const bf16x8*>(Wpsc + (s * 8 + cf) * 512 + laneoff);
      acc[0][cf] = __builtin_amdgcn_mfma_f32_16x16x32_bf16(ai[0][s], b, acc[0][cf], 0, 0, 0);
      acc[1][cf] = __builtin_amdgcn_mfma_f32_16x16x32_bf16(ai[1][s], b, acc[1][cf], 0, 0, 0);
    }
  #pragma unroll
  for (int m = 0; m < 2; ++m)
    #pragma unroll
    for (int cf = 0; cf < 8; ++cf) {
      int ch = cf * 16 + lr;
      #pragma unroll
      for (int r = 0; r < 4; ++r) {
        int row = rowbase + m * 16 + lh * 4 + r;
        if (row < NS) SCb[row * 128 + ch] = f2bf(acc[m][cf][r]);
      }
    }
  #pragma unroll
  for (int cf = 0; cf < 8; ++cf) {
    float s = 0.f, q = 0.f;
    #pragma unroll
    for (int m = 0; m < 2; ++m)
      #pragma unroll
      for (int r = 0; r < 4; ++r) { float v = acc[m][cf][r]; s += v; q += v * v; }
    s += __shfl_xor(s, 16); s += __shfl_xor(s, 32);
    q += __shfl_xor(q, 16); q += __shfl_xor(q, 32);
    if (lh == 0) {
      red[w * 256 + cf * 16 + lr] = s;
      red[w * 256 + 128 + cf * 16 + lr] = q;
    }
  }
  __syncthreads();
  if (t < 256)
    partial[(long)bid * 256 + t] =
        red[t] + red[256 + t] + red[512 + t] + red[768 + t];
}

// ---- gather-GEMM conv (R9/R15 optimum): 4 waves x 64 rows, wave tile 64x128.
// W in LDS (dbuf, global_load_lds, lane-linear); A gathered per-lane,
// conditional; single A reg buffer; counted-vmcnt barriers.
// FUSE_SC=true: blocks >= NB run the standalone shortcut body instead
// (block-level co-scheduling; conv path untouched). ----
template <int C, bool FUSE_SC>
__global__ __launch_bounds__(256, 2) void k_conv(
    const u16* __restrict__ X, const u16* __restrict__ Wp,
    const int* __restrict__ gidx,
    u16* __restrict__ Y, float* __restrict__ partial,
    const u16* __restrict__ Wpsc, u16* __restrict__ SCb,
    float* __restrict__ partsc) {
  constexpr int S = C / 32;
  constexpr int SLICE = C * 128;
  constexpr int NST = C / 16;
  constexpr int WAITN = NST + 4;
  __shared__ alignas(16) u16 Wbuf[2 * SLICE];
  __shared__ float red[1024];

  if constexpr (FUSE_SC) {
    if (blockIdx.x >= NB) {
      sc_body(blockIdx.x - NB, X, Wpsc, SCb, partsc, red);
      return;
    }
  }

  const int t = threadIdx.x, w = t >> 6, l = t & 63;
  const int lr = l & 15, lh = l >> 4;
  const int rowbase = blockIdx.x * 256 + w * 64;
  const int laneoff = l * 8;

  int rc[4]; bool ok[4];
  #pragma unroll
  for (int m = 0; m < 4; ++m) {
    int r = rowbase + m * 16 + lr;
    ok[m] = r < NS;
    rc[m] = ok[m] ? r : 0;
  }

  auto stage = [&](int k, int p) {
    #pragma unroll
    for (int i = 0; i < NST; ++i) {
      const u16* g = Wp + k * SLICE + (w * NST + i) * 512 + laneoff;
      u16* d = &Wbuf[p * SLICE + (w * NST + i) * 512];
      __builtin_amdgcn_global_load_lds(
          (const __attribute__((address_space(1))) u32*)g,
          (__attribute__((address_space(3))) u32*)d, 16, 0, 0);
    }
  };
  auto loadidx = [&](int k, int (&dst)[4]) {
    #pragma unroll
    for (int m = 0; m < 4; ++m) {
      int v = gidx[k * NS + rc[m]];
      dst[m] = ok[m] ? v : NS;
    }
  };
  auto gather = [&](const int (&src)[4], bf16x8 (&a)[4][S]) {
    #pragma unroll
    for (int m = 0; m < 4; ++m) {
      #pragma unroll
      for (int s = 0; s < S; ++s) a[m][s] = bf16x8{};
      if (src[m] != NS) {
        const u16* rowp = X + src[m] * C + lh * 8;
        #pragma unroll
        for (int s = 0; s < S; ++s)
          a[m][s] = *reinterpret_cast<const bf16x8*>(rowp + s * 32);
      }
    }
  };
  auto compute = [&](int p, const bf16x8 (&a)[4][S], f32x4 (&ac)[4][8]) {
    __builtin_amdgcn_s_setprio(1);
    #pragma unroll
    for (int s = 0; s < S; ++s)
      #pragma unroll
      for (int cf = 0; cf < 8; ++cf) {
        bf16x8 b = *reinterpret_cast<const bf16x8*>(
            &Wbuf[p * SLICE + (s * 8 + cf) * 512 + laneoff]);
        #pragma unroll
        for (int m = 0; m < 4; ++m)
          ac[m][cf] = __builtin_amdgcn_mfma_f32_16x16x32_bf16(a[m][s], b, ac[m][cf], 0, 0, 0);
      }
    __builtin_amdgcn_s_setprio(0);
  };

  f32x4 acc[4][8];
  #pragma unroll
  for (int m = 0; m < 4; ++m)
    #pragma unroll
    for (int cf = 0; cf < 8; ++cf) acc[m][cf] = (f32x4){0.f, 0.f, 0.f, 0.f};

  bf16x8 av[4][S];
  int sv0[4], sv1[4];

  loadidx(0, sv0);
  stage(0, 0);
  loadidx(1, sv1);
  gather(sv0, av);

  #pragma unroll 1
  for (int k = 0; k < NK - 1; k += 2) {
    stage(k + 1, 1);
    loadidx(k + 2, sv0);
    asm volatile("s_waitcnt vmcnt(%0)\n\ts_barrier" :: "i"(WAITN) : "memory");
    compute(0, av, acc);
    gather(sv1, av);
    asm volatile("s_waitcnt lgkmcnt(0)\n\ts_barrier" ::: "memory");
    stage(k + 2, 0);
    { int kn = (k + 3 < NK) ? k + 3 : NK - 1; loadidx(kn, sv1); }
    asm volatile("s_waitcnt vmcnt(%0)\n\ts_barrier" :: "i"(WAITN) : "memory");
    compute(1, av, acc);
    gather(sv0, av);
    asm volatile("s_waitcnt lgkmcnt(0)\n\ts_barrier" ::: "memory");
  }
  asm volatile("s_waitcnt vmcnt(0)\n\ts_barrier" ::: "memory");
  compute(0, av, acc);

  #pragma unroll
  for (int m = 0; m < 4; ++m)
    #pragma unroll
    for (int cf = 0; cf < 8; ++cf) {
      int ch = cf * 16 + lr;
      #pragma unroll
      for (int r = 0; r < 4; ++r) {
        int row = rowbase + m * 16 + lh * 4 + r;
        if (row < NS) Y[row * 128 + ch] = f2bf(acc[m][cf][r]);
      }
    }
  #pragma unroll
  for (int cf = 0; cf < 8; ++cf) {
    float s = 0.f, q = 0.f;
    #pragma unroll
    for (int m = 0; m < 4; ++m)
      #pragma unroll
      for (int r = 0; r < 4; ++r) { float v = acc[m][cf][r]; s += v; q += v * v; }
    s += __shfl_xor(s, 16); s += __shfl_xor(s, 32);
    q += __shfl_xor(q, 16); q += __shfl_xor(q, 32);
    if (lh == 0) {
      red[w * 256 + cf * 16 + lr] = s;
      red[w * 256 + 128 + cf * 16 + lr] = q;
    }
  }
  __syncthreads();
  if (t < 256)
    partial[blockIdx.x * 256 + t] =
        red[t] + red[256 + t] + red[512 + t] + red[768 + t];
}

// ---- deterministic reductions (rtmp stride 512) ----
__global__ void k_red1x2(const float* __restrict__ pa, const float* __restrict__ pb,
                         float* __restrict__ tmp) {
  int c = threadIdx.x;
  const float* p = (blockIdx.x == 0) ? pa : pb;
  int nrows = (blockIdx.x == 0) ? NB : NBSC;
  int roff  = (blockIdx.x == 0) ? 0 : 256;
  float s = 0.f;
  for (int r = blockIdx.y; r < nrows; r += 32) s += p[(long)r * 256 + c];
  tmp[(long)blockIdx.y * 512 + roff + c] = s;
}
__global__ void k_red1(const float* __restrict__ part, float* __restrict__ tmp,
                       int nrows) {
  int c = threadIdx.x;
  float s = 0.f;
  for (int r = blockIdx.y; r < nrows; r += 32) s += part[(long)r * 256 + c];
  tmp[(long)blockIdx.y * 512 + c] = s;
}
__global__ void k_red2(const float* __restrict__ tmp, float* __restrict__ out) {
  int c = blockIdx.x * 256 + threadIdx.x;
  float s = 0.f;
  #pragma unroll
  for (int r = 0; r < 32; ++r) s += tmp[(long)r * 512 + c];
  out[c] = s;
}

// ---- h = relu(bn1(y1)) -> bf16 ----
__global__ void k_bnrelu(const u16* __restrict__ Y1, const float* __restrict__ stats,
                         const float* __restrict__ g, const float* __restrict__ b,
                         u16* __restrict__ H) {
  long i8 = (long)blockIdx.x * 256 + threadIdx.x;
  const long tot = (long)NS * 16;
  if (i8 >= tot) return;
  int ch0 = ((int)i8 & 15) * 8;
  u16x8 y = *reinterpret_cast<const u16x8*>(Y1 + i8 * 8);
  u16x8 o;
  #pragma unroll
  for (int e = 0; e < 8; ++e) {
    int ch = ch0 + e;
    float m = stats[ch] * (1.f / NS);
    float var = stats[128 + ch] * (1.f / NS) - m * m;
    float a = g[ch] * rsqrtf(var + EPSV);
    float bb = b[ch] - m * a;
    float h = bf2f(y[e]) * a + bb;
    o[e] = f2bf(h > 0.f ? h : 0.f);
  }
  *reinterpret_cast<u16x8*>(H + i8 * 8) = o;
}

// ---- out = relu(bn2(y2) + bnsc(sc)) f32, 16B loads ----
__global__ void k_final(const u16* __restrict__ Y2, const u16* __restrict__ SCb,
                        const float* __restrict__ stats,
                        const float* __restrict__ g2, const float* __restrict__ b2,
                        const float* __restrict__ gsc, const float* __restrict__ bsc,
                        float* __restrict__ out) {
  long i8 = (long)blockIdx.x * 256 + threadIdx.x;
  if (i8 >= (long)NS * 16) return;
  int ch0 = ((int)i8 & 15) * 8;
  u16x8 y = *reinterpret_cast<const u16x8*>(Y2 + i8 * 8);
  u16x8 s = *reinterpret_cast<const u16x8*>(SCb + i8 * 8);
  f32x4 o0, o1;
  #pragma unroll
  for (int e = 0; e < 8; ++e) {
    int ch = ch0 + e;
    float m2 = stats[512 + ch] * (1.f / NS);
    float v2 = stats[640 + ch] * (1.f / NS) - m2 * m2;
    float a2 = g2[ch] * rsqrtf(v2 + EPSV);
    float msc = stats[256 + ch] * (1.f / NS);
    float vsc = stats[384 + ch] * (1.f / NS) - msc * msc;
    float asc = gsc[ch] * rsqrtf(vsc + EPSV);
    float val = bf2f(y[e]) * a2 + (b2[ch] - m2 * a2)
              + bf2f(s[e]) * asc + (bsc[ch] - msc * asc);
    float rv = val > 0.f ? val : 0.f;
    if (e < 4) o0[e] = rv; else o1[e - 4] = rv;
  }
  *reinterpret_cast<f32x4*>(out + i8 * 8) = o0;
  *reinterpret_cast<f32x4*>(out + i8 * 8 + 4) = o1;
}

extern "C" void kernel_launch(void* const* d_in, const int* in_sizes, int n_in,
                              void* d_out, int out_size, void* d_ws, size_t ws_size,
                              hipStream_t stream) {
  const float* feats = (const float*)d_in[0];
  const int* in_idx  = (const int*)d_in[1];
  const int* out_idx = (const int*)d_in[2];
  const float* W1  = (const float*)d_in[3];
  const float* g1  = (const float*)d_in[4];
  const float* b1  = (const float*)d_in[5];
  const float* W2  = (const float*)d_in[6];
  const float* g2  = (const float*)d_in[7];
  const float* b2  = (const float*)d_in[8];
  const float* Wsc = (const float*)d_in[9];
  const float* gsc = (const float*)d_in[10];
  const float* bsc = (const float*)d_in[11];

  char* ws = (char*)d_ws;
  size_t off = 0;
  auto alloc = [&](size_t bytes) {
    void* p = ws + off; off += (bytes + 255) & ~(size_t)255; return p;
  };
  float* stats = (float*)alloc(768 * 4);               // [s1,q1,ssc,qsc,s2,q2] x128
  float* rtmp  = (float*)alloc(32 * 512 * 4);          // reduce stage-1 (stride 512)
  u16* Xbf  = (u16*)alloc((size_t)NS * 64 * 2);
  u16* SCbf = (u16*)alloc((size_t)NS * 128 * 2);
  u16* Hbf  = (u16*)alloc((size_t)NS * 128 * 2);
  u16* Y2bf = (u16*)alloc((size_t)NS * 128 * 2);
  u16* Wp1  = (u16*)alloc((size_t)NK * 64 * 128 * 2);
  u16* Wp2  = (u16*)alloc((size_t)NK * 128 * 128 * 2);
  u16* Wpsc = (u16*)alloc((size_t)64 * 128 * 2);
  // d_out hosts y1 bf16 (51.2MB) + fused gidx (21.6MB); k_final overwrites
  u16* Y1bf = (u16*)d_out;
  int* gidx = (int*)((char*)d_out + (size_t)NS * 128 * 2);
  // partials alias Y2bf / Xbf regions (all consumed before their writers run)
  float* part1  = (float*)Y2bf;                  // conv1: 782x256
  float* partsc = part1 + (size_t)NB * 256;      // sc:   1563x256
  float* part2  = (float*)Xbf;                   // conv2 (Xbf dead after conv1)

  hipLaunchKernelGGL(k_prep_all, dim3(50000), dim3(256), 0, stream,
                     feats, in_idx, out_idx, W1, W2, Wsc,
                     Xbf, gidx, Wp1, Wp2, Wpsc, stats);
  // conv1 + shortcut co-scheduled in one dispatch: sc blocks backfill
  // conv1's latency bubbles and its dispatch tail.
  hipLaunchKernelGGL((k_conv<64, true>), dim3(NB + NBSC), dim3(256), 0, stream,
                     Xbf, Wp1, gidx, Y1bf, part1, Wpsc, SCbf, partsc);
  hipLaunchKernelGGL(k_red1x2, dim3(2, 32), dim3(256), 0, stream, part1, partsc, rtmp);
  hipLaunchKernelGGL(k_red2, dim3(2), dim3(256), 0, stream, rtmp, stats);
  hipLaunchKernelGGL(k_bnrelu, dim3(12500), dim3(256), 0, stream, Y1bf, stats, g1, b1, Hbf);
  hipLaunchKernelGGL((k_conv<128, false>), dim3(NB), dim3(256), 0, stream,
                     Hbf, Wp2, gidx, Y2bf, part2, nullptr, nullptr, nullptr);
  hipLaunchKernelGGL(k_red1, dim3(1, 32), dim3(256), 0, stream, part2, rtmp, NB);
  hipLaunchKernelGGL(k_red2, dim3(1), dim3(256), 0, stream, rtmp, stats + 512);
  hipLaunchKernelGGL(k_final, dim3(12500), dim3(256), 0, stream,
                     Y2bf, SCbf, stats, g2, b2, gsc, bsc, (float*)d_out);
}

// Round 19
// 385.403 us; speedup vs baseline: 1.4138x; 1.0519x over previous
//
#include <hip/hip_runtime.h>

#define NS 200000
#define NK 27
#define NB 782     // ceil(NS/256)  - conv blocks
#define NBSC 1563  // ceil(NS/128)  - shortcut blocks
#define EPSV 1e-5f

typedef __bf16 bf16x8 __attribute__((ext_vector_type(8)));
typedef float f32x4 __attribute__((ext_vector_type(4)));
typedef unsigned short u16;
typedef u16 u16x8 __attribute__((ext_vector_type(8)));
typedef u16 u16x4 __attribute__((ext_vector_type(4)));
typedef int i32x4 __attribute__((ext_vector_type(4)));
typedef unsigned u32;

__device__ __forceinline__ u16 f2bf(float f) {
  union { float f; unsigned u; } v; v.f = f;
  unsigned r = v.u + 0x7fffu + ((v.u >> 16) & 1u);
  return (u16)(r >> 16);
}
__device__ __forceinline__ float bf2f(u16 u) {
  union { unsigned u; float f; } v; v.u = ((unsigned)u) << 16;
  return v.f;
}

// ---- fused prep (vectorized): zero stats, feats f32->bf16 (8/thread),
// gidx fuse (8/thread), W pack (scalar; 2.5MB scatter, L2-absorbed) ----
// packed f = ((k*S+s)*8+cf)*512 + l*8 + j  <->  W[k][s*32+(l>>4)*8+j][cf*16+(l&15)]
__global__ void k_prep_all(const float* __restrict__ feats,
                           const int* __restrict__ in_idx, const int* __restrict__ out_idx,
                           const float* __restrict__ W1, const float* __restrict__ W2,
                           const float* __restrict__ Wsc,
                           u16* __restrict__ Xbf, int* __restrict__ gidx,
                           u16* __restrict__ Wp1, u16* __restrict__ Wp2,
                           u16* __restrict__ Wpsc, float* __restrict__ stats) {
  long i = (long)blockIdx.x * 256 + threadIdx.x;
  if (i < 768) stats[i] = 0.f;
  const long i8 = i * 8;
  // X: f32 -> bf16, 8 elements per thread (NS*64 = 12.8M, divisible by 8)
  if (i8 < (long)NS * 64) {
    f32x4 a = *reinterpret_cast<const f32x4*>(feats + i8);
    f32x4 b = *reinterpret_cast<const f32x4*>(feats + i8 + 4);
    u16x8 o;
    #pragma unroll
    for (int e = 0; e < 4; ++e) { o[e] = f2bf(a[e]); o[e + 4] = f2bf(b[e]); }
    *reinterpret_cast<u16x8*>(Xbf + i8) = o;
  }
  // gidx fuse, 8 per thread (NK*NS = 5.4M, divisible by 8)
  if (i8 < (long)NK * NS) {
    i32x4 ia = *reinterpret_cast<const i32x4*>(in_idx + i8);
    i32x4 ib = *reinterpret_cast<const i32x4*>(in_idx + i8 + 4);
    i32x4 oa = *reinterpret_cast<const i32x4*>(out_idx + i8);
    i32x4 ob = *reinterpret_cast<const i32x4*>(out_idx + i8 + 4);
    i32x4 ra, rb;
    #pragma unroll
    for (int e = 0; e < 4; ++e) {
      ra[e] = (oa[e] != NS) ? ia[e] : NS;
      rb[e] = (ob[e] != NS) ? ib[e] : NS;
    }
    *reinterpret_cast<i32x4*>(gidx + i8) = ra;
    *reinterpret_cast<i32x4*>(gidx + i8 + 4) = rb;
  }
  // W pack: scalar (671,744 elements < 1.6M threads)
  const int n1 = NK * 64 * 128, n2 = NK * 128 * 128, n3 = 64 * 128;
  if (i < (long)(n1 + n2 + n3)) {
    int ii = (int)i;
    const float* src; u16* dst; int f, S, C;
    if (ii < n1)           { src = W1;  dst = Wp1;  f = ii;           S = 2; C = 64; }
    else if (ii < n1 + n2) { src = W2;  dst = Wp2;  f = ii - n1;      S = 4; C = 128; }
    else                   { src = Wsc; dst = Wpsc; f = ii - n1 - n2; S = 2; C = 64; }
    int j = f & 7, l = (f >> 3) & 63, cf = (f >> 9) & 7;
    int rest = f >> 12;
    int s = rest % S, k = rest / S;
    int kk = s * 32 + (l >> 4) * 8 + j;
    dst[f] = f2bf(src[(k * C + kk) * 128 + cf * 16 + (l & 15)]);
  }
}

// ---- sc block body: SC = X @ Wsc, 128 rows, 4 waves x 32 rows ----
__device__ __forceinline__ void sc_body(
    int bid, const u16* __restrict__ X, const u16* __restrict__ Wpsc,
    u16* __restrict__ SCb, float* __restrict__ partial, float* red) {
  const int t = threadIdx.x, w = t >> 6, l = t & 63;
  const int lr = l & 15, lh = l >> 4;
  const int rowbase = bid * 128 + w * 32;
  const int laneoff = l * 8;

  bf16x8 ai[2][2];
  #pragma unroll
  for (int m = 0; m < 2; ++m) {
    int r = rowbase + m * 16 + lr;
    #pragma unroll
    for (int s = 0; s < 2; ++s) ai[m][s] = bf16x8{};
    if (r < NS) {
      const u16* rowp = X + r * 64 + lh * 8;
      ai[m][0] = *reinterpret_cast<const bf16x8*>(rowp);
      ai[m][1] = *reinterpret_cast<const bf16x8*>(rowp + 32);
    }
  }
  f32x4 acc[2][8];
  #pragma unroll
  for (int m = 0; m < 2; ++m)
    #pragma unroll
    for (int cf = 0; cf < 8; ++cf) acc[m][cf] = (f32x4){0.f, 0.f, 0.f, 0.f};
  #pragma unroll
  for (int s = 0; s < 2; ++s)
    #pragma unroll
    for (int cf = 0; cf < 8; ++cf) {
      bf16x8 b = *reinterpret_cast<const bf16x8*>(Wpsc + (s * 8 + cf) * 512 + laneoff);
      acc[0][cf] = __builtin_amdgcn_mfma_f32_16x16x32_bf16(ai[0][s], b, acc[0][cf], 0, 0, 0);
      acc[1][cf] = __builtin_amdgcn_mfma_f32_16x16x32_bf16(ai[1][s], b, acc[1][cf], 0, 0, 0);
    }
  #pragma unroll
  for (int m = 0; m < 2; ++m)
    #pragma unroll
    for (int cf = 0; cf < 8; ++cf) {
      int ch = cf * 16 + lr;
      #pragma unroll
      for (int r = 0; r < 4; ++r) {
        int row = rowbase + m * 16 + lh * 4 + r;
        if (row < NS) SCb[row * 128 + ch] = f2bf(acc[m][cf][r]);
      }
    }
  #pragma unroll
  for (int cf = 0; cf < 8; ++cf) {
    float s = 0.f, q = 0.f;
    #pragma unroll
    for (int m = 0; m < 2; ++m)
      #pragma unroll
      for (int r = 0; r < 4; ++r) { float v = acc[m][cf][r]; s += v; q += v * v; }
    s += __shfl_xor(s, 16); s += __shfl_xor(s, 32);
    q += __shfl_xor(q, 16); q += __shfl_xor(q, 32);
    if (lh == 0) {
      red[w * 256 + cf * 16 + lr] = s;
      red[w * 256 + 128 + cf * 16 + lr] = q;
    }
  }
  __syncthreads();
  if (t < 256)
    partial[(long)bid * 256 + t] =
        red[t] + red[256 + t] + red[512 + t] + red[768 + t];
}

// ---- gather-GEMM conv (R9/R15 optimum): 4 waves x 64 rows, wave tile 64x128.
// W in LDS (dbuf, global_load_lds, lane-linear); A gathered per-lane,
// conditional; single A reg buffer; counted-vmcnt barriers.
// FUSE_SC=true: blocks >= NB run the standalone shortcut body instead. ----
template <int C, bool FUSE_SC>
__global__ __launch_bounds__(256, 2) void k_conv(
    const u16* __restrict__ X, const u16* __restrict__ Wp,
    const int* __restrict__ gidx,
    u16* __restrict__ Y, float* __restrict__ partial,
    const u16* __restrict__ Wpsc, u16* __restrict__ SCb,
    float* __restrict__ partsc) {
  constexpr int S = C / 32;
  constexpr int SLICE = C * 128;
  constexpr int NST = C / 16;
  constexpr int WAITN = NST + 4;
  __shared__ alignas(16) u16 Wbuf[2 * SLICE];
  __shared__ float red[1024];

  if constexpr (FUSE_SC) {
    if (blockIdx.x >= NB) {
      sc_body(blockIdx.x - NB, X, Wpsc, SCb, partsc, red);
      return;
    }
  }

  const int t = threadIdx.x, w = t >> 6, l = t & 63;
  const int lr = l & 15, lh = l >> 4;
  const int rowbase = blockIdx.x * 256 + w * 64;
  const int laneoff = l * 8;

  int rc[4]; bool ok[4];
  #pragma unroll
  for (int m = 0; m < 4; ++m) {
    int r = rowbase + m * 16 + lr;
    ok[m] = r < NS;
    rc[m] = ok[m] ? r : 0;
  }

  auto stage = [&](int k, int p) {
    #pragma unroll
    for (int i = 0; i < NST; ++i) {
      const u16* g = Wp + k * SLICE + (w * NST + i) * 512 + laneoff;
      u16* d = &Wbuf[p * SLICE + (w * NST + i) * 512];
      __builtin_amdgcn_global_load_lds(
          (const __attribute__((address_space(1))) u32*)g,
          (__attribute__((address_space(3))) u32*)d, 16, 0, 0);
    }
  };
  auto loadidx = [&](int k, int (&dst)[4]) {
    #pragma unroll
    for (int m = 0; m < 4; ++m) {
      int v = gidx[k * NS + rc[m]];
      dst[m] = ok[m] ? v : NS;
    }
  };
  auto gather = [&](const int (&src)[4], bf16x8 (&a)[4][S]) {
    #pragma unroll
    for (int m = 0; m < 4; ++m) {
      #pragma unroll
      for (int s = 0; s < S; ++s) a[m][s] = bf16x8{};
      if (src[m] != NS) {
        const u16* rowp = X + src[m] * C + lh * 8;
        #pragma unroll
        for (int s = 0; s < S; ++s)
          a[m][s] = *reinterpret_cast<const bf16x8*>(rowp + s * 32);
      }
    }
  };
  auto compute = [&](int p, const bf16x8 (&a)[4][S], f32x4 (&ac)[4][8]) {
    __builtin_amdgcn_s_setprio(1);
    #pragma unroll
    for (int s = 0; s < S; ++s)
      #pragma unroll
      for (int cf = 0; cf < 8; ++cf) {
        bf16x8 b = *reinterpret_cast<const bf16x8*>(
            &Wbuf[p * SLICE + (s * 8 + cf) * 512 + laneoff]);
        #pragma unroll
        for (int m = 0; m < 4; ++m)
          ac[m][cf] = __builtin_amdgcn_mfma_f32_16x16x32_bf16(a[m][s], b, ac[m][cf], 0, 0, 0);
      }
    __builtin_amdgcn_s_setprio(0);
  };

  f32x4 acc[4][8];
  #pragma unroll
  for (int m = 0; m < 4; ++m)
    #pragma unroll
    for (int cf = 0; cf < 8; ++cf) acc[m][cf] = (f32x4){0.f, 0.f, 0.f, 0.f};

  bf16x8 av[4][S];
  int sv0[4], sv1[4];

  loadidx(0, sv0);
  stage(0, 0);
  loadidx(1, sv1);
  gather(sv0, av);

  #pragma unroll 1
  for (int k = 0; k < NK - 1; k += 2) {
    stage(k + 1, 1);
    loadidx(k + 2, sv0);
    asm volatile("s_waitcnt vmcnt(%0)\n\ts_barrier" :: "i"(WAITN) : "memory");
    compute(0, av, acc);
    gather(sv1, av);
    asm volatile("s_waitcnt lgkmcnt(0)\n\ts_barrier" ::: "memory");
    stage(k + 2, 0);
    { int kn = (k + 3 < NK) ? k + 3 : NK - 1; loadidx(kn, sv1); }
    asm volatile("s_waitcnt vmcnt(%0)\n\ts_barrier" :: "i"(WAITN) : "memory");
    compute(1, av, acc);
    gather(sv0, av);
    asm volatile("s_waitcnt lgkmcnt(0)\n\ts_barrier" ::: "memory");
  }
  asm volatile("s_waitcnt vmcnt(0)\n\ts_barrier" ::: "memory");
  compute(0, av, acc);

  #pragma unroll
  for (int m = 0; m < 4; ++m)
    #pragma unroll
    for (int cf = 0; cf < 8; ++cf) {
      int ch = cf * 16 + lr;
      #pragma unroll
      for (int r = 0; r < 4; ++r) {
        int row = rowbase + m * 16 + lh * 4 + r;
        if (row < NS) Y[row * 128 + ch] = f2bf(acc[m][cf][r]);
      }
    }
  #pragma unroll
  for (int cf = 0; cf < 8; ++cf) {
    float s = 0.f, q = 0.f;
    #pragma unroll
    for (int m = 0; m < 4; ++m)
      #pragma unroll
      for (int r = 0; r < 4; ++r) { float v = acc[m][cf][r]; s += v; q += v * v; }
    s += __shfl_xor(s, 16); s += __shfl_xor(s, 32);
    q += __shfl_xor(q, 16); q += __shfl_xor(q, 32);
    if (lh == 0) {
      red[w * 256 + cf * 16 + lr] = s;
      red[w * 256 + 128 + cf * 16 + lr] = q;
    }
  }
  __syncthreads();
  if (t < 256)
    partial[blockIdx.x * 256 + t] =
        red[t] + red[256 + t] + red[512 + t] + red[768 + t];
}

// ---- deterministic reductions (rtmp stride 512) ----
__global__ void k_red1x2(const float* __restrict__ pa, const float* __restrict__ pb,
                         float* __restrict__ tmp) {
  int c = threadIdx.x;
  const float* p = (blockIdx.x == 0) ? pa : pb;
  int nrows = (blockIdx.x == 0) ? NB : NBSC;
  int roff  = (blockIdx.x == 0) ? 0 : 256;
  float s = 0.f;
  for (int r = blockIdx.y; r < nrows; r += 32) s += p[(long)r * 256 + c];
  tmp[(long)blockIdx.y * 512 + roff + c] = s;
}
__global__ void k_red1(const float* __restrict__ part, float* __restrict__ tmp,
                       int nrows) {
  int c = threadIdx.x;
  float s = 0.f;
  for (int r = blockIdx.y; r < nrows; r += 32) s += part[(long)r * 256 + c];
  tmp[(long)blockIdx.y * 512 + c] = s;
}
__global__ void k_red2(const float* __restrict__ tmp, float* __restrict__ out) {
  int c = blockIdx.x * 256 + threadIdx.x;
  float s = 0.f;
  #pragma unroll
  for (int r = 0; r < 32; ++r) s += tmp[(long)r * 512 + c];
  out[c] = s;
}

// ---- h = relu(bn1(y1)) -> bf16 ----
__global__ void k_bnrelu(const u16* __restrict__ Y1, const float* __restrict__ stats,
                         const float* __restrict__ g, const float* __restrict__ b,
                         u16* __restrict__ H) {
  long i8 = (long)blockIdx.x * 256 + threadIdx.x;
  const long tot = (long)NS * 16;
  if (i8 >= tot) return;
  int ch0 = ((int)i8 & 15) * 8;
  u16x8 y = *reinterpret_cast<const u16x8*>(Y1 + i8 * 8);
  u16x8 o;
  #pragma unroll
  for (int e = 0; e < 8; ++e) {
    int ch = ch0 + e;
    float m = stats[ch] * (1.f / NS);
    float var = stats[128 + ch] * (1.f / NS) - m * m;
    float a = g[ch] * rsqrtf(var + EPSV);
    float bb = b[ch] - m * a;
    float h = bf2f(y[e]) * a + bb;
    o[e] = f2bf(h > 0.f ? h : 0.f);
  }
  *reinterpret_cast<u16x8*>(H + i8 * 8) = o;
}

// ---- out = relu(bn2(y2) + bnsc(sc)) f32, 16B loads ----
__global__ void k_final(const u16* __restrict__ Y2, const u16* __restrict__ SCb,
                        const float* __restrict__ stats,
                        const float* __restrict__ g2, const float* __restrict__ b2,
                        const float* __restrict__ gsc, const float* __restrict__ bsc,
                        float* __restrict__ out) {
  long i8 = (long)blockIdx.x * 256 + threadIdx.x;
  if (i8 >= (long)NS * 16) return;
  int ch0 = ((int)i8 & 15) * 8;
  u16x8 y = *reinterpret_cast<const u16x8*>(Y2 + i8 * 8);
  u16x8 s = *reinterpret_cast<const u16x8*>(SCb + i8 * 8);
  f32x4 o0, o1;
  #pragma unroll
  for (int e = 0; e < 8; ++e) {
    int ch = ch0 + e;
    float m2 = stats[512 + ch] * (1.f / NS);
    float v2 = stats[640 + ch] * (1.f / NS) - m2 * m2;
    float a2 = g2[ch] * rsqrtf(v2 + EPSV);
    float msc = stats[256 + ch] * (1.f / NS);
    float vsc = stats[384 + ch] * (1.f / NS) - msc * msc;
    float asc = gsc[ch] * rsqrtf(vsc + EPSV);
    float val = bf2f(y[e]) * a2 + (b2[ch] - m2 * a2)
              + bf2f(s[e]) * asc + (bsc[ch] - msc * asc);
    float rv = val > 0.f ? val : 0.f;
    if (e < 4) o0[e] = rv; else o1[e - 4] = rv;
  }
  *reinterpret_cast<f32x4*>(out + i8 * 8) = o0;
  *reinterpret_cast<f32x4*>(out + i8 * 8 + 4) = o1;
}

extern "C" void kernel_launch(void* const* d_in, const int* in_sizes, int n_in,
                              void* d_out, int out_size, void* d_ws, size_t ws_size,
                              hipStream_t stream) {
  const float* feats = (const float*)d_in[0];
  const int* in_idx  = (const int*)d_in[1];
  const int* out_idx = (const int*)d_in[2];
  const float* W1  = (const float*)d_in[3];
  const float* g1  = (const float*)d_in[4];
  const float* b1  = (const float*)d_in[5];
  const float* W2  = (const float*)d_in[6];
  const float* g2  = (const float*)d_in[7];
  const float* b2  = (const float*)d_in[8];
  const float* Wsc = (const float*)d_in[9];
  const float* gsc = (const float*)d_in[10];
  const float* bsc = (const float*)d_in[11];

  char* ws = (char*)d_ws;
  size_t off = 0;
  auto alloc = [&](size_t bytes) {
    void* p = ws + off; off += (bytes + 255) & ~(size_t)255; return p;
  };
  float* stats = (float*)alloc(768 * 4);               // [s1,q1,ssc,qsc,s2,q2] x128
  float* rtmp  = (float*)alloc(32 * 512 * 4);          // reduce stage-1 (stride 512)
  u16* Xbf  = (u16*)alloc((size_t)NS * 64 * 2);
  u16* SCbf = (u16*)alloc((size_t)NS * 128 * 2);
  u16* Hbf  = (u16*)alloc((size_t)NS * 128 * 2);
  u16* Y2bf = (u16*)alloc((size_t)NS * 128 * 2);
  u16* Wp1  = (u16*)alloc((size_t)NK * 64 * 128 * 2);
  u16* Wp2  = (u16*)alloc((size_t)NK * 128 * 128 * 2);
  u16* Wpsc = (u16*)alloc((size_t)64 * 128 * 2);
  // d_out hosts y1 bf16 (51.2MB) + fused gidx (21.6MB); k_final overwrites
  u16* Y1bf = (u16*)d_out;
  int* gidx = (int*)((char*)d_out + (size_t)NS * 128 * 2);
  // partials alias Y2bf / Xbf regions (all consumed before their writers run)
  float* part1  = (float*)Y2bf;                  // conv1: 782x256
  float* partsc = part1 + (size_t)NB * 256;      // sc:   1563x256
  float* part2  = (float*)Xbf;                   // conv2 (Xbf dead after conv1)

  hipLaunchKernelGGL(k_prep_all, dim3(6250), dim3(256), 0, stream,
                     feats, in_idx, out_idx, W1, W2, Wsc,
                     Xbf, gidx, Wp1, Wp2, Wpsc, stats);
  // conv1 + shortcut co-scheduled in one dispatch
  hipLaunchKernelGGL((k_conv<64, true>), dim3(NB + NBSC), dim3(256), 0, stream,
                     Xbf, Wp1, gidx, Y1bf, part1, Wpsc, SCbf, partsc);
  hipLaunchKernelGGL(k_red1x2, dim3(2, 32), dim3(256), 0, stream, part1, partsc, rtmp);
  hipLaunchKernelGGL(k_red2, dim3(2), dim3(256), 0, stream, rtmp, stats);
  hipLaunchKernelGGL(k_bnrelu, dim3(12500), dim3(256), 0, stream, Y1bf, stats, g1, b1, Hbf);
  hipLaunchKernelGGL((k_conv<128, false>), dim3(NB), dim3(256), 0, stream,
                     Hbf, Wp2, gidx, Y2bf, part2, nullptr, nullptr, nullptr);
  hipLaunchKernelGGL(k_red1, dim3(1, 32), dim3(256), 0, stream, part2, rtmp, NB);
  hipLaunchKernelGGL(k_red2, dim3(1), dim3(256), 0, stream, rtmp, stats + 512);
  hipLaunchKernelGGL(k_final, dim3(12500), dim3(256), 0, stream,
                     Y2bf, SCbf, stats, g2, b2, gsc, bsc, (float*)d_out);
}